// Round 1
// baseline (127.301 us; speedup 1.0000x reference)
//
#include <hip/hip_runtime.h>
#include <hip/hip_bf16.h>

#define EPSW 1e-6f

typedef __attribute__((ext_vector_type(4))) float floatx4;
typedef __attribute__((ext_vector_type(8))) short shortx8;   // 8 bf16 (4 VGPRs)

// round-to-nearest-even float -> bf16 bits (finite inputs)
__device__ __forceinline__ unsigned short f2bf(float f) {
    unsigned int u = __float_as_uint(f);
    u = (u + 0x7fffu + ((u >> 16) & 1u)) >> 16;
    return (unsigned short)u;
}

// ---------------------------------------------------------------------------
// Kernel 1: build normalized adjacency A[dst][src] (dense 64x64, fp32).
// deg[d] = sum of clamped edge weights into d + 1 (self loop).
// A[d][s] += dinv[s]*w*dinv[d];  A[n][n] += dinv[n]^2.
// ---------------------------------------------------------------------------
__global__ __launch_bounds__(256) void build_A(const int* __restrict__ ei,
                                               const float* __restrict__ ew,
                                               float* __restrict__ Ag) {
    __shared__ float deg[64];
    __shared__ float dinv[64];
    __shared__ float A[4096];
    const int t = threadIdx.x;
    if (t < 64) deg[t] = 1.0f;                  // self-loop weight pre-added
    for (int i = t; i < 4096; i += 256) A[i] = 0.0f;
    __syncthreads();
    const int* src = ei;
    const int* dst = ei + 4096;
    for (int e = t; e < 4096; e += 256) {
        float w = ew[e];
        w = (w <= 0.0f) ? EPSW : w;
        atomicAdd(&deg[dst[e]], w);
    }
    __syncthreads();
    if (t < 64) dinv[t] = 1.0f / sqrtf(deg[t]);  // deg >= 1 always
    __syncthreads();
    for (int e = t; e < 4096; e += 256) {
        float w = ew[e];
        w = (w <= 0.0f) ? EPSW : w;
        const int s = src[e], d = dst[e];
        atomicAdd(&A[d * 64 + s], dinv[s] * w * dinv[d]);
    }
    if (t < 64) atomicAdd(&A[t * 64 + t], dinv[t] * dinv[t]);
    __syncthreads();
    for (int i = t; i < 4096; i += 256) Ag[i] = A[i];
}

// ---------------------------------------------------------------------------
// Kernel 2: M = A @ A   (64x64x64, fp32). 16 blocks x 256 threads,
// one output element per thread, A staged in LDS.
// ---------------------------------------------------------------------------
__global__ __launch_bounds__(256) void build_M(const float* __restrict__ Ag,
                                               float* __restrict__ Mg) {
    __shared__ float A[4096];
    const int t = threadIdx.x;
    for (int i = t; i < 4096; i += 256) A[i] = Ag[i];
    __syncthreads();
    const int r = blockIdx.x * 4 + (t >> 6);
    const int c = t & 63;
    float s = 0.0f;
#pragma unroll 8
    for (int k = 0; k < 64; ++k) s += A[r * 64 + k] * A[k * 64 + c];
    Mg[r * 64 + c] = s;
}

// ---------------------------------------------------------------------------
// Kernel 3: z[r][h] += sum_k x[r][k] * W[h][k]   (2048 x 128, K=2000)
// bf16 MFMA 16x16x32. Block tile: 32 rows x 128 h. Grid: 64 row-tiles x
// 4 K-splits (K-chunk 500, 16-byte aligned: 500*4B=2000B). fp32 atomicAdd
// into z. Tail chunk (k=480..499) zero-padded in LDS.
// Wave w: rows (w>>1)*16..+16, h (w&1)*64..+64 (4 MFMA tiles of 16).
// A-frag: x[m=lane&15][k=(lane>>4)*8+j]; B-frag: W[h=lane&15][same k]
// (both 16B-contiguous in LDS). C/D: row=(lane>>4)*4+reg, col=lane&15.
// LDS stride 40 bf16 (80B): rows r and r+8 share banks -> 2-way (free).
// ---------------------------------------------------------------------------
__global__ __launch_bounds__(256) void gemm_xw(const float* __restrict__ x,
                                               const float* __restrict__ W,
                                               float* __restrict__ z) {
    __shared__ alignas(16) unsigned short xs[32][40];
    __shared__ alignas(16) unsigned short wsm[128][40];
    const int rbase  = blockIdx.x * 32;
    const int kbase0 = blockIdx.y * 500;
    const int t    = threadIdx.x;
    const int wave = t >> 6, lane = t & 63;
    const int m = lane & 15, q = lane >> 4;

    floatx4 acc[4];
#pragma unroll
    for (int c = 0; c < 4; ++c) acc[c] = (floatx4){0.f, 0.f, 0.f, 0.f};

    const int srow = t >> 3;          // 0..31
    const int kc   = (t & 7) * 4;     // 0..28, float4 granule

    for (int kk = 0; kk < 500; kk += 32) {
        const int kglob  = kbase0 + kk;
        const int kvalid = (500 - kk < 32) ? (500 - kk) : 32;  // 32 or 20
        // stage x tile: 32 rows x 32 k
        {
            floatx4 v = (floatx4){0.f, 0.f, 0.f, 0.f};
            if (kc < kvalid)
                v = *(const floatx4*)(x + (size_t)(rbase + srow) * 2000 + kglob + kc);
            unsigned short* p = &xs[srow][kc];
            p[0] = f2bf(v.x); p[1] = f2bf(v.y); p[2] = f2bf(v.z); p[3] = f2bf(v.w);
        }
        // stage W tile: 128 rows x 32 k
#pragma unroll
        for (int j = 0; j < 4; ++j) {
            const int wrow = srow + 32 * j;
            floatx4 v = (floatx4){0.f, 0.f, 0.f, 0.f};
            if (kc < kvalid)
                v = *(const floatx4*)(W + (size_t)wrow * 2000 + kglob + kc);
            unsigned short* p = &wsm[wrow][kc];
            p[0] = f2bf(v.x); p[1] = f2bf(v.y); p[2] = f2bf(v.z); p[3] = f2bf(v.w);
        }
        __syncthreads();
        const shortx8 af = *(const shortx8*)&xs[(wave >> 1) * 16 + m][q * 8];
#pragma unroll
        for (int c = 0; c < 4; ++c) {
            const shortx8 bf = *(const shortx8*)&wsm[(wave & 1) * 64 + c * 16 + m][q * 8];
            acc[c] = __builtin_amdgcn_mfma_f32_16x16x32_bf16(af, bf, acc[c], 0, 0, 0);
        }
        __syncthreads();
    }

    const int rowt = rbase + (wave >> 1) * 16 + q * 4;
#pragma unroll
    for (int c = 0; c < 4; ++c) {
        const int h = (wave & 1) * 64 + c * 16 + m;
#pragma unroll
        for (int v = 0; v < 4; ++v)
            atomicAdd(&z[(size_t)(rowt + v) * 128 + h], acc[c][v]);
    }
}

// ---------------------------------------------------------------------------
// Kernel 4: y[b][n][h] = bias[h] + sum_m M[n][m] * z[b*64+m][h]
// Grid: 32 batches x 4 h-chunks of 32. M (16KB) + z-chunk (8KB) in LDS.
// ---------------------------------------------------------------------------
__global__ __launch_bounds__(256) void apply_M(const float* __restrict__ z,
                                               const float* __restrict__ Mg,
                                               const float* __restrict__ bias,
                                               float* __restrict__ y) {
    __shared__ float Ms[4096];
    __shared__ float zs[64][32];
    const int b  = blockIdx.x;
    const int hc = blockIdx.y;
    const int t  = threadIdx.x;
    for (int i = t; i < 4096; i += 256) Ms[i] = Mg[i];
    for (int i = t; i < 2048; i += 256) {
        const int mm = i >> 5, hh = i & 31;
        zs[mm][hh] = z[(size_t)(b * 64 + mm) * 128 + hc * 32 + hh];
    }
    __syncthreads();
    const int h  = t & 31;
    const int n0 = (t >> 5) * 8;
    const float bv = bias[hc * 32 + h];
#pragma unroll
    for (int r = 0; r < 8; ++r) {
        const int n = n0 + r;
        float s = bv;
#pragma unroll 8
        for (int mm = 0; mm < 64; ++mm) s += Ms[n * 64 + mm] * zs[mm][h];
        y[(size_t)b * 8192 + n * 128 + hc * 32 + h] = s;
    }
}

extern "C" void kernel_launch(void* const* d_in, const int* in_sizes, int n_in,
                              void* d_out, int out_size, void* d_ws, size_t ws_size,
                              hipStream_t stream) {
    const float* x    = (const float*)d_in[0];   // (32,8,64,250) fp32 = (2048,2000)
    const int*   ei   = (const int*)d_in[1];     // (2,4096) int
    const float* ew   = (const float*)d_in[2];   // (4096,)
    const float* W    = (const float*)d_in[3];   // (128,2000)
    const float* bias = (const float*)d_in[4];   // (128,)
    float* y = (float*)d_out;                    // (32,64,128) fp32

    float* z  = (float*)d_ws;                    // 2048*128 fp32 = 1 MB
    float* Ag = z + 262144;                      // 64*64
    float* Mg = Ag + 4096;                       // 64*64

    hipMemsetAsync(z, 0, 262144 * sizeof(float), stream);
    build_A<<<1, 256, 0, stream>>>(ei, ew, Ag);
    build_M<<<16, 256, 0, stream>>>(Ag, Mg);
    gemm_xw<<<dim3(64, 4), 256, 0, stream>>>(x, W, z);
    apply_M<<<dim3(32, 4), 256, 0, stream>>>(z, Mg, bias, y);
}

// Round 2
// 103.447 us; speedup vs baseline: 1.2306x; 1.2306x over previous
//
#include <hip/hip_runtime.h>
#include <hip/hip_bf16.h>

#define EPSW 1e-6f

typedef __attribute__((ext_vector_type(4))) float floatx4;
typedef __attribute__((ext_vector_type(8))) short shortx8;   // 8 bf16 (4 VGPRs)

// round-to-nearest-even float -> bf16 bits (finite inputs)
__device__ __forceinline__ unsigned short f2bf(float f) {
    unsigned int u = __float_as_uint(f);
    u = (u + 0x7fffu + ((u >> 16) & 1u)) >> 16;
    return (unsigned short)u;
}

// ---------------------------------------------------------------------------
// prep: one dispatch, 273 blocks x 256 threads.
//   blocks 0..255 : xt transpose. x (2048 rows x 2000 K fp32) -> xt bf16 in
//                   MFMA-A-fragment layout [kg][row][8], kg = k/8, K padded
//                   to 2048 (kg 0..255) with zeros. Block = 64 rows x 32 kg.
//   blocks 256..271: wt transform. W (128 x 2000 fp32) -> wt bf16 [kg][h][8],
//                   zero-padded like xt.
//   block 272     : A (normalized adjacency, dense 64x64) and Mt = (A@A)^T.
// ---------------------------------------------------------------------------
__global__ __launch_bounds__(256) void prep(const float* __restrict__ x,
                                            const float* __restrict__ W,
                                            const int* __restrict__ ei,
                                            const float* __restrict__ ew,
                                            unsigned short* __restrict__ xt,
                                            unsigned short* __restrict__ wt,
                                            float* __restrict__ Mt) {
    __shared__ __align__(16) unsigned char smem[64 * 264 * 2];  // 33792 B
    const int bid = blockIdx.x;
    const int t   = threadIdx.x;

    if (bid < 256) {
        // ---- xt transpose tile: rows rb..rb+63, kg kgb..kgb+31 ----
        unsigned short(*tile)[264] = (unsigned short(*)[264])smem;  // +8 pad
        const int rb   = (bid >> 3) * 64;      // 32 row-tiles
        const int kgb  = (bid & 7) * 32;       // 8 kg-tiles
        const int kbas = kgb * 8;              // k base (multiple of 256)
        // phase 1: coalesced fp32 reads -> bf16 LDS tile
#pragma unroll
        for (int i = 0; i < 16; ++i) {
            const int idx = i * 256 + t;
            const int r   = idx >> 6;          // 0..63
            const int kc  = (idx & 63) * 4;    // 0..252
            const int k   = kbas + kc;
            floatx4 v = (floatx4){0.f, 0.f, 0.f, 0.f};
            if (k < 2000)
                v = *(const floatx4*)(x + (size_t)(rb + r) * 2000 + k);
            tile[r][kc + 0] = f2bf(v.x);
            tile[r][kc + 1] = f2bf(v.y);
            tile[r][kc + 2] = f2bf(v.z);
            tile[r][kc + 3] = f2bf(v.w);
        }
        __syncthreads();
        // phase 2: 16B granules out, coalesced over rows
#pragma unroll
        for (int i = 0; i < 8; ++i) {
            const int kg_l = i * 4 + (t >> 6);  // wave-uniform
            const int r    = t & 63;
            const shortx8 g = *(const shortx8*)&tile[r][kg_l * 8];
            *(shortx8*)(xt + ((size_t)(kgb + kg_l) * 2048 + rb + r) * 8) = g;
        }
    } else if (bid < 272) {
        // ---- wt transform ----
#pragma unroll
        for (int i = 0; i < 8; ++i) {
            const int G  = (bid - 256) * 2048 + i * 256 + t;  // 0..32767
            const int kg = G >> 7;
            const int h  = G & 127;
            const int k  = kg * 8;
            floatx4 v0 = (floatx4){0.f, 0.f, 0.f, 0.f};
            floatx4 v1 = (floatx4){0.f, 0.f, 0.f, 0.f};
            if (k < 2000) {  // kg<=249 -> whole granule valid
                v0 = *(const floatx4*)(W + (size_t)h * 2000 + k);
                v1 = *(const floatx4*)(W + (size_t)h * 2000 + k + 4);
            }
            unsigned short* p = wt + ((size_t)kg * 128 + h) * 8;
            p[0] = f2bf(v0.x); p[1] = f2bf(v0.y); p[2] = f2bf(v0.z); p[3] = f2bf(v0.w);
            p[4] = f2bf(v1.x); p[5] = f2bf(v1.y); p[6] = f2bf(v1.z); p[7] = f2bf(v1.w);
        }
    } else {
        // ---- A + Mt in one block ----
        float* A    = (float*)smem;            // 4096 f
        float* deg  = (float*)(smem + 16384);  // 64 f
        float* dinv = deg + 64;                // 64 f
        if (t < 64) deg[t] = 1.0f;             // self-loop pre-added
        for (int i = t; i < 4096; i += 256) A[i] = 0.0f;
        __syncthreads();
        const int* src = ei;
        const int* dst = ei + 4096;
        for (int e = t; e < 4096; e += 256) {
            float w = ew[e];
            w = (w <= 0.0f) ? EPSW : w;
            atomicAdd(&deg[dst[e]], w);
        }
        __syncthreads();
        if (t < 64) dinv[t] = 1.0f / sqrtf(deg[t]);
        __syncthreads();
        for (int e = t; e < 4096; e += 256) {
            float w = ew[e];
            w = (w <= 0.0f) ? EPSW : w;
            const int s = src[e], d = dst[e];
            atomicAdd(&A[d * 64 + s], dinv[s] * w * dinv[d]);
        }
        if (t < 64) atomicAdd(&A[t * 64 + t], dinv[t] * dinv[t]);
        __syncthreads();
        // Mt[c][n] = (A@A)[n][c]
#pragma unroll
        for (int i = 0; i < 16; ++i) {
            const int idx = i * 256 + t;
            const int n = idx >> 6, c = idx & 63;
            float s = 0.0f;
#pragma unroll 8
            for (int k = 0; k < 64; ++k) s += A[n * 64 + k] * A[k * 64 + c];
            Mt[c * 64 + n] = s;
        }
    }
}

// ---------------------------------------------------------------------------
// gemm: z[r][h] = sum_k x[r][k]*W[h][k].  Barrier-free, LDS-free.
// Grid (128 row-tiles of 16, 2 h-halves of 64) x 256 thr. Wave w owns one
// 16x16 tile: rows rbase..+16, h = by*64 + w*16..+16, K = 2048 (64 MFMA).
// A/B frags load straight from xt/wt (pre-baked fragment layouts):
//   lane(m,q): A granule (kt*4+q)*2048 + rbase+m ; B granule (kt*4+q)*128+h+m
// 2 accumulators break the MFMA dep chain; unroll 4 -> 8 loads in flight.
// ---------------------------------------------------------------------------
__global__ __launch_bounds__(256) void gemm(const unsigned short* __restrict__ xt,
                                            const unsigned short* __restrict__ wt,
                                            float* __restrict__ z) {
    const int t    = threadIdx.x;
    const int wave = t >> 6, lane = t & 63;
    const int m = lane & 15, q = lane >> 4;
    const int rbase = blockIdx.x * 16;
    const int hbase = blockIdx.y * 64 + wave * 16;

    const shortx8* Ag = (const shortx8*)xt;
    const shortx8* Bg = (const shortx8*)wt;
    int ga = q * 2048 + rbase + m;   // +8192 per kt
    int gb = q * 128 + hbase + m;    // +512  per kt

    floatx4 acc0 = (floatx4){0.f, 0.f, 0.f, 0.f};
    floatx4 acc1 = (floatx4){0.f, 0.f, 0.f, 0.f};
#pragma unroll 4
    for (int kt = 0; kt < 64; kt += 2) {
        const shortx8 a0 = Ag[ga];
        const shortx8 b0 = Bg[gb];
        const shortx8 a1 = Ag[ga + 8192];
        const shortx8 b1 = Bg[gb + 512];
        acc0 = __builtin_amdgcn_mfma_f32_16x16x32_bf16(a0, b0, acc0, 0, 0, 0);
        acc1 = __builtin_amdgcn_mfma_f32_16x16x32_bf16(a1, b1, acc1, 0, 0, 0);
        ga += 16384; gb += 1024;
    }
#pragma unroll
    for (int v = 0; v < 4; ++v)
        z[(size_t)(rbase + q * 4 + v) * 128 + hbase + m] = acc0[v] + acc1[v];
}

// ---------------------------------------------------------------------------
// apply_M: y[b][n][h] = bias[h] + sum_m M[n][m] * z[b*64+m][h]
// Grid (32 b, 8 h-chunks of 16) x 256 thr. Mt indexing (Mt[m*64+n]) makes the
// per-instr LDS pattern 4 distinct banks x 16-lane broadcast: conflict-free.
// ---------------------------------------------------------------------------
__global__ __launch_bounds__(256) void apply_M(const float* __restrict__ z,
                                               const float* __restrict__ Mtg,
                                               const float* __restrict__ bias,
                                               float* __restrict__ y) {
    __shared__ float Ms[4096];
    __shared__ float zs[64][16];
    const int b  = blockIdx.x;
    const int hc = blockIdx.y;
    const int t  = threadIdx.x;
#pragma unroll
    for (int i = 0; i < 16; ++i) Ms[i * 256 + t] = Mtg[i * 256 + t];
#pragma unroll
    for (int i = 0; i < 4; ++i) {
        const int idx = i * 256 + t;
        const int mr = idx >> 4, hh = idx & 15;
        zs[mr][hh] = z[(size_t)(b * 64 + mr) * 128 + hc * 16 + hh];
    }
    __syncthreads();
    const int h  = t & 15;
    const int n0 = (t >> 4) * 4;
    const float bv = bias[hc * 16 + h];
    float s0 = bv, s1 = bv, s2 = bv, s3 = bv;
#pragma unroll
    for (int mm = 0; mm < 64; ++mm) {
        const float zv = zs[mm][h];
        s0 += Ms[mm * 64 + n0 + 0] * zv;
        s1 += Ms[mm * 64 + n0 + 1] * zv;
        s2 += Ms[mm * 64 + n0 + 2] * zv;
        s3 += Ms[mm * 64 + n0 + 3] * zv;
    }
    float* yp = y + (size_t)b * 8192 + (size_t)n0 * 128 + hc * 16 + h;
    yp[0]   = s0;
    yp[128] = s1;
    yp[256] = s2;
    yp[384] = s3;
}

extern "C" void kernel_launch(void* const* d_in, const int* in_sizes, int n_in,
                              void* d_out, int out_size, void* d_ws, size_t ws_size,
                              hipStream_t stream) {
    const float* x    = (const float*)d_in[0];   // (2048, 2000) fp32
    const int*   ei   = (const int*)d_in[1];     // (2, 4096)
    const float* ew   = (const float*)d_in[2];   // (4096,)
    const float* W    = (const float*)d_in[3];   // (128, 2000) fp32
    const float* bias = (const float*)d_in[4];   // (128,)
    float* y = (float*)d_out;                    // (32, 64, 128) fp32

    float* z  = (float*)d_ws;                    // 262144 f  (1 MB)
    float* Mt = z + 262144;                      // 4096 f
    unsigned short* xt = (unsigned short*)(Mt + 4096);   // 256*2048*8 bf16 (8 MB)
    unsigned short* wt = xt + 4194304;                   // 256*128*8 bf16 (512 KB)

    prep<<<273, 256, 0, stream>>>(x, W, ei, ew, xt, wt, Mt);
    gemm<<<dim3(128, 2), 256, 0, stream>>>(xt, wt, z);
    apply_M<<<dim3(32, 8), 256, 0, stream>>>(z, Mt, bias, y);
}